// Round 1
// baseline (9472.585 us; speedup 1.0000x reference)
//
#include <hip/hip_runtime.h>

// Problem constants
#define SEQ    1024
#define HD     2048
#define NLAYER 2
#define NG     4      // groups
#define DH     64     // head dim
#define GSUB   8      // subheads per group
#define FF_SZ  8192
#define VOCAB  38400

// ---------------------------------------------------------------------------
// Generic batched tiled GEMM: C = alpha * A@B (+bias) (optional relu)
// A: [M,K] lda, B: [K,N] ldb, C: [M,N] ldc; batch via blockIdx.z with strides.
// Requires M%64==0, N%64==0, K%16==0 (true for all call sites here).
// 64x64 tile, BK=16, 256 threads, 4x4 per thread.
// ---------------------------------------------------------------------------
__global__ __launch_bounds__(256)
void gemm_kernel(const float* __restrict__ A, const float* __restrict__ B,
                 const float* __restrict__ bias, float* __restrict__ C,
                 int M, int N, int K, int lda, int ldb, int ldc,
                 long long sA, long long sB, long long sC,
                 float alpha, int relu) {
    A += (long long)blockIdx.z * sA;
    B += (long long)blockIdx.z * sB;
    C += (long long)blockIdx.z * sC;

    __shared__ float As[16][64 + 1];   // As[k][m]
    __shared__ float Bs[16][64 + 1];   // Bs[k][n]

    const int tid = threadIdx.x;
    const int tx = tid & 15;          // 0..15 -> col group
    const int ty = tid >> 4;          // 0..15 -> row group
    const int row0 = blockIdx.y * 64;
    const int col0 = blockIdx.x * 64;

    float acc[4][4] = {};

    for (int k0 = 0; k0 < K; k0 += 16) {
        // Load A tile: 64 rows x 16 k-cols (1024 elems, 4 per thread)
        #pragma unroll
        for (int i = 0; i < 4; ++i) {
            int e = tid + i * 256;
            int r = e >> 4;       // 0..63
            int c = e & 15;       // 0..15
            As[c][r] = A[(long long)(row0 + r) * lda + (k0 + c)];
        }
        // Load B tile: 16 k-rows x 64 cols
        #pragma unroll
        for (int i = 0; i < 4; ++i) {
            int e = tid + i * 256;
            int r = e >> 6;       // 0..15
            int c = e & 63;       // 0..63
            Bs[r][c] = B[(long long)(k0 + r) * ldb + (col0 + c)];
        }
        __syncthreads();

        #pragma unroll
        for (int kk = 0; kk < 16; ++kk) {
            float a[4], b[4];
            #pragma unroll
            for (int i = 0; i < 4; ++i) a[i] = As[kk][ty * 4 + i];
            #pragma unroll
            for (int j = 0; j < 4; ++j) b[j] = Bs[kk][tx * 4 + j];
            #pragma unroll
            for (int i = 0; i < 4; ++i)
                #pragma unroll
                for (int j = 0; j < 4; ++j)
                    acc[i][j] += a[i] * b[j];
        }
        __syncthreads();
    }

    #pragma unroll
    for (int i = 0; i < 4; ++i) {
        int r = row0 + ty * 4 + i;
        #pragma unroll
        for (int j = 0; j < 4; ++j) {
            int c = col0 + tx * 4 + j;
            float v = acc[i][j] * alpha;
            if (bias) v += bias[c];
            if (relu) v = fmaxf(v, 0.0f);
            C[(long long)r * ldc + c] = v;
        }
    }
}

// ---------------------------------------------------------------------------
// Embedding: h[s,c] = tok_emb[ids[s], c] + pos_emb[s, c]
// ---------------------------------------------------------------------------
__global__ __launch_bounds__(256)
void embed_kernel(const int* __restrict__ ids, const float* __restrict__ tok,
                  const float* __restrict__ pos, float* __restrict__ h) {
    int idx = blockIdx.x * 256 + threadIdx.x;
    if (idx >= SEQ * HD) return;
    int s = idx >> 11;            // / HD
    int c = idx & (HD - 1);
    h[idx] = tok[(long long)ids[s] * HD + c] + pos[idx];
}

// ---------------------------------------------------------------------------
// qsum: qs[g][s][d] = sum_j q[s][g*512 + j*64 + d]
// ---------------------------------------------------------------------------
__global__ __launch_bounds__(256)
void qsum_kernel(const float* __restrict__ q, float* __restrict__ qs) {
    int idx = blockIdx.x * 256 + threadIdx.x;   // over NG*SEQ*DH = 262144
    if (idx >= NG * SEQ * DH) return;
    int d = idx & (DH - 1);
    int s = (idx >> 6) & (SEQ - 1);
    int g = idx >> 16;
    const float* base = q + (long long)s * HD + g * (GSUB * DH) + d;
    float acc = 0.0f;
    #pragma unroll
    for (int j = 0; j < GSUB; ++j) acc += base[j * DH];
    qs[idx] = acc;   // layout [g][s][d] contiguous == ((g*SEQ)+s)*DH+d
}

// ---------------------------------------------------------------------------
// k transpose: kT[g][d][t] = k[t][g*64 + d]
// ---------------------------------------------------------------------------
__global__ __launch_bounds__(256)
void ktrans_kernel(const float* __restrict__ k, float* __restrict__ kT) {
    int idx = blockIdx.x * 256 + threadIdx.x;   // over NG*DH*SEQ = 262144
    if (idx >= NG * DH * SEQ) return;
    int t = idx & (SEQ - 1);
    int d = (idx >> 10) & (DH - 1);
    int g = idx >> 16;
    kT[idx] = k[(long long)t * (NG * DH) + g * DH + d];
}

// ---------------------------------------------------------------------------
// Row softmax over 1024 columns; rows = NG*SEQ
// ---------------------------------------------------------------------------
__global__ __launch_bounds__(256)
void softmax_kernel(float* __restrict__ sc) {
    float* p = sc + (long long)blockIdx.x * SEQ;
    int tid = threadIdx.x;
    __shared__ float red[256];

    float vals[4];
    float mx = -1e30f;
    #pragma unroll
    for (int i = 0; i < 4; ++i) {
        vals[i] = p[tid + i * 256];
        mx = fmaxf(mx, vals[i]);
    }
    red[tid] = mx; __syncthreads();
    for (int s = 128; s > 0; s >>= 1) {
        if (tid < s) red[tid] = fmaxf(red[tid], red[tid + s]);
        __syncthreads();
    }
    mx = red[0]; __syncthreads();

    float sum = 0.0f;
    #pragma unroll
    for (int i = 0; i < 4; ++i) {
        vals[i] = expf(vals[i] - mx);
        sum += vals[i];
    }
    red[tid] = sum; __syncthreads();
    for (int s = 128; s > 0; s >>= 1) {
        if (tid < s) red[tid] += red[tid + s];
        __syncthreads();
    }
    float inv = 1.0f / red[0];
    #pragma unroll
    for (int i = 0; i < 4; ++i) p[tid + i * 256] = vals[i] * inv;
}

// ---------------------------------------------------------------------------
// Broadcast ctx[g][s][d] -> ctxf[s][g*512 + j*64 + d] for all j
// ---------------------------------------------------------------------------
__global__ __launch_bounds__(256)
void bcast_kernel(const float* __restrict__ ctx, float* __restrict__ ctxf) {
    int idx = blockIdx.x * 256 + threadIdx.x;   // over SEQ*HD
    if (idx >= SEQ * HD) return;
    int c = idx & (HD - 1);
    int s = idx >> 11;
    int g = c >> 9;               // / 512
    int d = c & (DH - 1);
    ctxf[idx] = ctx[((long long)g * SEQ + s) * DH + d];
}

// ---------------------------------------------------------------------------
// Fused residual + LayerNorm over HD=2048 per row.
// out[r,:] = LN(h[r,:] + (x ? x[r,:] : 0)) * g + b
// ---------------------------------------------------------------------------
__global__ __launch_bounds__(256)
void add_ln_kernel(const float* __restrict__ h, const float* __restrict__ x,
                   const float* __restrict__ gamma, const float* __restrict__ beta,
                   float* __restrict__ out) {
    int row = blockIdx.x;
    int tid = threadIdx.x;
    const float* hp = h + (long long)row * HD;
    const float* xp = x ? x + (long long)row * HD : nullptr;
    float* op = out + (long long)row * HD;

    float y[8];
    float sum = 0.0f, sumsq = 0.0f;
    #pragma unroll
    for (int i = 0; i < 8; ++i) {
        int c = tid + i * 256;
        float v = hp[c];
        if (xp) v += xp[c];
        y[i] = v;
        sum += v;
        sumsq += v * v;
    }
    __shared__ float r1[256], r2[256];
    r1[tid] = sum; r2[tid] = sumsq; __syncthreads();
    for (int s = 128; s > 0; s >>= 1) {
        if (tid < s) { r1[tid] += r1[tid + s]; r2[tid] += r2[tid + s]; }
        __syncthreads();
    }
    float mean = r1[0] * (1.0f / HD);
    float var  = r2[0] * (1.0f / HD) - mean * mean;
    float rstd = rsqrtf(var + 1e-5f);
    #pragma unroll
    for (int i = 0; i < 8; ++i) {
        int c = tid + i * 256;
        op[c] = (y[i] - mean) * rstd * gamma[c] + beta[c];
    }
}

// ---------------------------------------------------------------------------
// Host-side launch
// ---------------------------------------------------------------------------
static void launch_gemm(hipStream_t st, const float* A, const float* B,
                        const float* bias, float* C, int M, int N, int K,
                        int lda, int ldb, int ldc,
                        long long sA, long long sB, long long sC, int batch,
                        float alpha, int relu) {
    dim3 grid(N / 64, M / 64, batch);
    gemm_kernel<<<grid, dim3(256), 0, st>>>(A, B, bias, C, M, N, K,
                                            lda, ldb, ldc, sA, sB, sC,
                                            alpha, relu);
}

extern "C" void kernel_launch(void* const* d_in, const int* in_sizes, int n_in,
                              void* d_out, int out_size, void* d_ws, size_t ws_size,
                              hipStream_t stream) {
    const int*   ids     = (const int*)  d_in[0];
    const float* tok_emb = (const float*)d_in[1];
    const float* pos_emb = (const float*)d_in[2];
    const float* Wq      = (const float*)d_in[3];
    const float* bq      = (const float*)d_in[4];
    const float* Wk      = (const float*)d_in[5];
    const float* bk      = (const float*)d_in[6];
    const float* Wv      = (const float*)d_in[7];
    const float* bv      = (const float*)d_in[8];
    const float* Wo      = (const float*)d_in[9];
    const float* bo      = (const float*)d_in[10];
    const float* g1      = (const float*)d_in[11];
    const float* be1     = (const float*)d_in[12];
    const float* W1      = (const float*)d_in[13];
    const float* b1      = (const float*)d_in[14];
    const float* W2      = (const float*)d_in[15];
    const float* b2      = (const float*)d_in[16];
    const float* g2      = (const float*)d_in[17];
    const float* be2     = (const float*)d_in[18];
    const float* lnf_g   = (const float*)d_in[19];
    const float* lnf_b   = (const float*)d_in[20];
    const float* Whead   = (const float*)d_in[21];

    float* ws = (float*)d_ws;
    const long long M2 = (long long)SEQ * HD;        // 2M floats
    const long long MS = (long long)NG * SEQ * DH;   // 256K floats

    float* h     = ws;                       // 2M
    float* bufB  = h + M2;                   // 2M  (q / attn_out / ffn_out)
    float* qs    = bufB + M2;                // 256K
    float* kbuf  = qs + MS;                  // 256K
    float* vbuf  = kbuf + MS;                // 256K
    float* kT    = vbuf + MS;                // 256K
    float* ctx   = kT + MS;                  // 256K
    float* bufD  = ctx + MS;                 // 2M  (ctx_full / final-LN out)
    float* bufC  = bufD + M2;                // 8M  (scores 4M / ffn mid 8M)

    const int nElem = SEQ * HD;

    // Embedding
    embed_kernel<<<dim3((nElem + 255) / 256), dim3(256), 0, stream>>>(
        ids, tok_emb, pos_emb, h);

    for (int l = 0; l < NLAYER; ++l) {
        const float* Wq_l = Wq + (long long)l * HD * HD;
        const float* bq_l = bq + (long long)l * HD;
        const float* Wk_l = Wk + (long long)l * HD * (NG * DH);
        const float* bk_l = bk + (long long)l * (NG * DH);
        const float* Wv_l = Wv + (long long)l * HD * (NG * DH);
        const float* bv_l = bv + (long long)l * (NG * DH);
        const float* Wo_l = Wo + (long long)l * HD * HD;
        const float* bo_l = bo + (long long)l * HD;
        const float* g1_l = g1 + (long long)l * HD;
        const float* be1_l = be1 + (long long)l * HD;
        const float* W1_l = W1 + (long long)l * HD * FF_SZ;
        const float* b1_l = b1 + (long long)l * FF_SZ;
        const float* W2_l = W2 + (long long)l * FF_SZ * HD;
        const float* b2_l = b2 + (long long)l * HD;
        const float* g2_l = g2 + (long long)l * HD;
        const float* be2_l = be2 + (long long)l * HD;

        // q = h @ Wq + bq   [S, HD]
        launch_gemm(stream, h, Wq_l, bq_l, bufB, SEQ, HD, HD,
                    HD, HD, HD, 0, 0, 0, 1, 1.0f, 0);
        // k = h @ Wk + bk   [S, 256]
        launch_gemm(stream, h, Wk_l, bk_l, kbuf, SEQ, NG * DH, HD,
                    HD, NG * DH, NG * DH, 0, 0, 0, 1, 1.0f, 0);
        // v = h @ Wv + bv   [S, 256]
        launch_gemm(stream, h, Wv_l, bv_l, vbuf, SEQ, NG * DH, HD,
                    HD, NG * DH, NG * DH, 0, 0, 0, 1, 1.0f, 0);

        // qs[g][s][d] = sum_j q[s][g,j,d]
        qsum_kernel<<<dim3((NG * SEQ * DH + 255) / 256), dim3(256), 0, stream>>>(
            bufB, qs);
        // kT[g][d][t]
        ktrans_kernel<<<dim3((NG * DH * SEQ + 255) / 256), dim3(256), 0, stream>>>(
            kbuf, kT);

        // scores[g] = qs[g] @ kT[g] / 8   [S,S] per group
        launch_gemm(stream, qs, kT, nullptr, bufC, SEQ, SEQ, DH,
                    DH, SEQ, SEQ,
                    (long long)SEQ * DH, (long long)DH * SEQ,
                    (long long)SEQ * SEQ, NG, 0.125f, 0);

        // softmax rows
        softmax_kernel<<<dim3(NG * SEQ), dim3(256), 0, stream>>>(bufC);

        // ctx[g] = attn[g] @ v[:, g*64:(g+1)*64]   [S, 64] per group
        launch_gemm(stream, bufC, vbuf, nullptr, ctx, SEQ, DH, SEQ,
                    SEQ, NG * DH, DH,
                    (long long)SEQ * SEQ, (long long)DH,
                    (long long)SEQ * DH, NG, 1.0f, 0);

        // broadcast -> ctx_full [S, HD]
        bcast_kernel<<<dim3((nElem + 255) / 256), dim3(256), 0, stream>>>(
            ctx, bufD);

        // attn_out = ctx_full @ Wo + bo
        launch_gemm(stream, bufD, Wo_l, bo_l, bufB, SEQ, HD, HD,
                    HD, HD, HD, 0, 0, 0, 1, 1.0f, 0);

        // h = LN(h + attn_out) * g1 + be1   (in place)
        add_ln_kernel<<<dim3(SEQ), dim3(256), 0, stream>>>(h, bufB, g1_l, be1_l, h);

        // mid = relu(h @ W1 + b1)   [S, FF]
        launch_gemm(stream, h, W1_l, b1_l, bufC, SEQ, FF_SZ, HD,
                    HD, FF_SZ, FF_SZ, 0, 0, 0, 1, 1.0f, 1);

        // ffn_out = mid @ W2 + b2   [S, HD]
        launch_gemm(stream, bufC, W2_l, b2_l, bufB, SEQ, HD, FF_SZ,
                    FF_SZ, HD, HD, 0, 0, 0, 1, 1.0f, 0);

        // h = LN(h + ffn_out) * g2 + be2
        add_ln_kernel<<<dim3(SEQ), dim3(256), 0, stream>>>(h, bufB, g2_l, be2_l, h);
    }

    // final LN (no residual)
    add_ln_kernel<<<dim3(SEQ), dim3(256), 0, stream>>>(h, nullptr, lnf_g, lnf_b, bufD);

    // logits = h_ln @ Whead   [S, VOCAB]
    launch_gemm(stream, bufD, Whead, nullptr, (float*)d_out, SEQ, VOCAB, HD,
                HD, VOCAB, VOCAB, 0, 0, 0, 1, 1.0f, 0);

    (void)in_sizes; (void)n_in; (void)out_size; (void)ws_size;
}